// Round 16
// baseline (320.081 us; speedup 1.0000x reference)
//
#include <hip/hip_runtime.h>
#include <math.h>
#include <limits.h>

#define N_SAMP 512
#define C_IN   12
#define L_IN   8192
#define NDIL   6
#define NFILT  30
#define NFEAT  180
#define NCHUNK 4
#define CHUNK  (L_IN / NCHUNK)   // 2048
#define EPSV   1e-5f

#define HALO   160               // 5 * max dilation(32)
#define TLC    1024              // positions per stage tile
#define LWC    (TLC + 2*HALO)    // 1344 staged rows
#define LWCP   (LWC + 32)        // +32 pad rows: zero-tap overhang reads
#define CELLS  (LWCP + (LWCP >> 4) + 1)   // 1463 cells
#define TILEB  (CELLS * 16)      // 23408 bytes per (A|B) part
#define NST    (CHUNK / TLC)     // 2 stages per block

// ws layout: [0, WF_OFF) float partials; then wc, wd (i8 frag tables), bias
#define WF_OFF (3 * N_SAMP * NCHUNK * NFILT * 2)   // 368640 floats
#define WTAB_B (NDIL * 3 * 64 * 16)                // 18432 bytes per table

typedef __attribute__((ext_vector_type(4))) int i32x4;

// Padded-linear cell map (round-14 winner): one pad cell every 16 rows.
__device__ __forceinline__ int cellb(int r) {
    return (r + (r >> 4)) << 4;   // byte offset of row r's 16B cell
}

__device__ __forceinline__ int imax(int a, int b) { return a > b ? a : b; }

// a1 split into a1x (A.D) and a1y (B.C): MFMA dep chains 6-deep -> 3-deep.
__device__ __forceinline__ void mfma_step(const i32x4 ah, const i32x4 al,
                                          const i32x4 C, const i32x4 D,
                                          i32x4& a0, i32x4& a1x,
                                          i32x4& a1y, i32x4& a2)
{
    a0  = __builtin_amdgcn_mfma_i32_16x16x64_i8(ah, C, a0,  0, 0, 0);
    a1x = __builtin_amdgcn_mfma_i32_16x16x64_i8(ah, D, a1x, 0, 0, 0);
    a1y = __builtin_amdgcn_mfma_i32_16x16x64_i8(al, C, a1y, 0, 0, 0);
    a2  = __builtin_amdgcn_mfma_i32_16x16x64_i8(al, D, a2,  0, 0, 0);
}

__device__ __forceinline__ void tile_stats(const i32x4 a0, const i32x4 a1x,
                                           const i32x4 a1y, const i32x4 a2,
                                           int tj, int& cnt_i, int& mx_i)
{
    const int v0 = (((a0[0] << 8) + a1x[0] + a1y[0]) << 8) + a2[0];
    const int v1 = (((a0[1] << 8) + a1x[1] + a1y[1]) << 8) + a2[1];
    const int v2 = (((a0[2] << 8) + a1x[2] + a1y[2]) << 8) + a2[2];
    const int v3 = (((a0[3] << 8) + a1x[3] + a1y[3]) << 8) + a2[3];
    cnt_i += (v0 > tj) + (v1 > tj) + (v2 > tj) + (v3 > tj);
    mx_i = imax(mx_i, imax(imax(v0, v1), imax(v2, v3)));
}

// ---------------------------------------------------------------------------
// Build i8 B-fragment tables: W = round(w*8192) = 256*C + D.
// Tap assignment per dilation j (must match conv row offsets):
//   j <= 3: tap = mf*4 + q   (read stride 4d rows)
//   j >= 4: tap = 3*q + mf   (read stride  d rows)
// tap 11 is zero-weighted padding in both schemes.
// ---------------------------------------------------------------------------
__global__ __launch_bounds__(256)
void build_wb(const float* __restrict__ W7, const float* __restrict__ W9,
              const float* __restrict__ W11, const float* __restrict__ b7,
              const float* __restrict__ b9, const float* __restrict__ b11,
              signed char* __restrict__ wc, signed char* __restrict__ wd,
              float* __restrict__ bias_tab)
{
    const int t = blockIdx.x * 256 + threadIdx.x;
    if (t < NDIL * 3 * 64) {
        const int j    = t / 192;
        const int mf   = (t / 64) % 3;
        const int lane = t % 64;
        const int col  = lane & 15;
        const int q    = lane >> 4;
        const int tap  = (j >= 4) ? (3 * q + mf) : (mf * 4 + q);
#pragma unroll
        for (int e = 0; e < 16; ++e) {
            float v = 0.0f;
            if (col < 15 && tap <= 10 && e < 12) {
                const int toff = tap - 5;
                if (col < 5) {
                    if (toff >= -3 && toff <= 3)
                        v = W7[((j * 5 + col) * 12 + e) * 7 + toff + 3];
                } else if (col < 10) {
                    if (toff >= -4 && toff <= 4)
                        v = W9[((j * 5 + col - 5) * 12 + e) * 9 + toff + 4];
                } else {
                    v = W11[((j * 5 + col - 10) * 12 + e) * 11 + toff + 5];
                }
            }
            const int W  = __float2int_rn(v * 8192.0f);
            const int C8 = (W + 128) >> 8;      // in [-32, 32]
            const int D8 = W - (C8 << 8);       // in [-128, 127]
            wc[(size_t)t * 16 + e] = (signed char)C8;
            wd[(size_t)t * 16 + e] = (signed char)D8;
        }
    } else if (t < NDIL * 3 * 64 + 96) {
        const int i = t - NDIL * 3 * 64;
        const int j = i / 16, s = i % 16;
        float b = 0.0f;
        if (s < 5)       b = b7 [j * 5 + s];
        else if (s < 10) b = b9 [j * 5 + s - 5];
        else if (s < 15) b = b11[j * 5 + s - 10];
        bias_tab[j * 16 + s] = b;
    }
}

// ---------------------------------------------------------------------------
// i8 MFMA conv, EXACT 4-term fixed-point product (bit-identical to r14/r15):
//   X = round(x*4096) = 256A + B;  W = round(w*8192) = 256C + D
//   X*W = 65536*(A.C) + 256*(A.D + B.C) + B.D  (exact in wrapping i32).
// Round-16: (1) win5 -> two-pass win3 (even/odd tiles, 32-row steps): same
// reads, window registers 40 -> 24 VGPR; (2) d=2 windowed via its stride-8
// alias (step2@t == step0@t+1): 96 -> 66 reads; (3) a1 accumulator split
// (3-deep MFMA chains). MFMA pipe (157 us, information-minimal 12/tile-dil)
// is the binding resource; these changes feed it.
// NOTE: no min-occupancy launch_bounds arg (rounds 2/7 spill lesson).
// ---------------------------------------------------------------------------
__global__ __launch_bounds__(256)
void rocket_conv_i8(const float* __restrict__ x,
                    const signed char* __restrict__ wc,
                    const signed char* __restrict__ wd,
                    const float* __restrict__ bias_tab,
                    float* __restrict__ ws)
{
    __shared__ __align__(16) signed char xq[2][TILEB];   // A | B, 46816 B
    __shared__ int scnt[NDIL * 16];                      // [j][col]
    __shared__ int smx [NDIL * 16];

    const int ch  = blockIdx.x;
    const int n   = blockIdx.y;
    const int tid = threadIdx.x;
    const int lane = tid & 63, wv = tid >> 6;
    const int row_l = lane & 15, q = lane >> 4;
    const float* __restrict__ xrow = x + (size_t)n * C_IN * L_IN;
    const i32x4* __restrict__ wcv = (const i32x4*)wc;
    const i32x4* __restrict__ wdv = (const i32x4*)wd;

    if (tid < NDIL * 16) { scnt[tid] = 0; smx[tid] = INT_MIN; }

#define RDH(ROW) (*(const i32x4*)&xq[0][cellb(ROW)])
#define RDL(ROW) (*(const i32x4*)&xq[1][cellb(ROW)])

    auto flush = [&](int j, int cnt_i, int mx_i) {
        cnt_i += __shfl_xor(cnt_i, 16);
        cnt_i += __shfl_xor(cnt_i, 32);
        mx_i = imax(mx_i, __shfl_xor(mx_i, 16));
        mx_i = imax(mx_i, __shfl_xor(mx_i, 32));
        if (lane < 16) {
            atomicAdd(&scnt[j * 16 + lane], cnt_i);
            atomicMax(&smx[j * 16 + lane], mx_i);
        }
    };

    // depth-3 window: tap-group read stride == 16 rows (1 tile step)
    auto win3 = [&](int j, int lane_off) {
        const i32x4 C0 = wcv[(j * 3 + 0) * 64 + lane];
        const i32x4 C1 = wcv[(j * 3 + 1) * 64 + lane];
        const i32x4 C2 = wcv[(j * 3 + 2) * 64 + lane];
        const i32x4 D0 = wdv[(j * 3 + 0) * 64 + lane];
        const i32x4 D1 = wdv[(j * 3 + 1) * 64 + lane];
        const i32x4 D2 = wdv[(j * 3 + 2) * 64 + lane];
        const int tj = (int)floorf(bias_tab[j * 16 + row_l] * -33554432.0f);
        const int rb = HALO + wv * 256 + row_l + lane_off;
        i32x4 h0 = RDH(rb),      l0 = RDL(rb);
        i32x4 h1 = RDH(rb + 16), l1 = RDL(rb + 16);
        int cnt_i = 0, mx_i = INT_MIN;
#pragma unroll
        for (int t = 0; t < 16; ++t) {
            i32x4 h2 = RDH(rb + 16 * (t + 2));
            i32x4 l2 = RDL(rb + 16 * (t + 2));
            i32x4 a0 = {0,0,0,0}, a1x = {0,0,0,0};
            i32x4 a1y = {0,0,0,0}, a2 = {0,0,0,0};
            mfma_step(h0, l0, C0, D0, a0, a1x, a1y, a2);
            mfma_step(h1, l1, C1, D1, a0, a1x, a1y, a2);
            mfma_step(h2, l2, C2, D2, a0, a1x, a1y, a2);
            tile_stats(a0, a1x, a1y, a2, tj, cnt_i, mx_i);
            h0 = h1; l0 = l1; h1 = h2; l1 = l2;
        }
        flush(j, cnt_i, mx_i);
    };

    // two-pass depth-3 window for 32-row tap-group strides: pass 0 = even
    // tiles, pass 1 = odd tiles; each pass steps 32 rows -> depth-3 window.
    // Same read count as depth-5, but 24 VGPR of slots instead of 40.
    auto win3x2 = [&](int j, int lane_off) {
        const i32x4 C0 = wcv[(j * 3 + 0) * 64 + lane];
        const i32x4 C1 = wcv[(j * 3 + 1) * 64 + lane];
        const i32x4 C2 = wcv[(j * 3 + 2) * 64 + lane];
        const i32x4 D0 = wdv[(j * 3 + 0) * 64 + lane];
        const i32x4 D1 = wdv[(j * 3 + 1) * 64 + lane];
        const i32x4 D2 = wdv[(j * 3 + 2) * 64 + lane];
        const int tj = (int)floorf(bias_tab[j * 16 + row_l] * -33554432.0f);
        const int rb = HALO + wv * 256 + row_l + lane_off;
        int cnt_i = 0, mx_i = INT_MIN;
#pragma unroll
        for (int par = 0; par < 2; ++par) {
            const int base = rb + 16 * par;
            i32x4 h0 = RDH(base),      l0 = RDL(base);
            i32x4 h1 = RDH(base + 32), l1 = RDL(base + 32);
#pragma unroll
            for (int p = 0; p < 8; ++p) {
                i32x4 h2 = RDH(base + 32 * (p + 2));
                i32x4 l2 = RDL(base + 32 * (p + 2));
                i32x4 a0 = {0,0,0,0}, a1x = {0,0,0,0};
                i32x4 a1y = {0,0,0,0}, a2 = {0,0,0,0};
                mfma_step(h0, l0, C0, D0, a0, a1x, a1y, a2);
                mfma_step(h1, l1, C1, D1, a0, a1x, a1y, a2);
                mfma_step(h2, l2, C2, D2, a0, a1x, a1y, a2);
                tile_stats(a0, a1x, a1y, a2, tj, cnt_i, mx_i);
                h0 = h1; l0 = l1; h1 = h2; l1 = l2;
            }
        }
        flush(j, cnt_i, mx_i);
    };

    const int c0 = ch * CHUNK;
#pragma unroll 1
    for (int st = 0; st < NST; ++st) {
        const int t0 = c0 + st * TLC;
        __syncthreads();   // covers stats init on st==0, xq reuse after
        // ---- stage: quantize x to (A,B) i8 pairs, padded 16B cells ----
#pragma unroll 1
        for (int r = tid; r < LWC; r += 256) {
            const int g = t0 - HALO + r;
            int h[4] = {0, 0, 0, 0}, l[4] = {0, 0, 0, 0};
            if ((unsigned)g < (unsigned)L_IN) {
#pragma unroll
                for (int c = 0; c < 12; ++c) {
                    const float xv = xrow[c * L_IN + g];
                    const int X  = __float2int_rn(xv * 4096.0f);
                    const int A8 = (X + 128) >> 8;     // [-91, 91]
                    const int B8 = X - (A8 << 8);      // [-128, 127]
                    h[c >> 2] |= (A8 & 255) << ((c & 3) * 8);
                    l[c >> 2] |= (B8 & 255) << ((c & 3) * 8);
                }
            }
            const int cell = cellb(r);
            *(i32x4*)&xq[0][cell] = (i32x4){h[0], h[1], h[2], h[3]};
            *(i32x4*)&xq[1][cell] = (i32x4){l[0], l[1], l[2], l[3]};
        }
        __syncthreads();

        // ---- d=1: generic 6-read path (no window alignment exists) ----
        {
            const int j = 0;
            const i32x4 C0 = wcv[0 * 64 + lane];
            const i32x4 C1 = wcv[1 * 64 + lane];
            const i32x4 C2 = wcv[2 * 64 + lane];
            const i32x4 D0 = wdv[0 * 64 + lane];
            const i32x4 D1 = wdv[1 * 64 + lane];
            const i32x4 D2 = wdv[2 * 64 + lane];
            const int tj = (int)floorf(bias_tab[row_l] * -33554432.0f);
            const int rb0 = HALO + wv * 256 + row_l + (q - 5);
            const int rb1 = rb0 + 4;          // taps q, q+4, q+8 (11 -> 0 wt)
            const int rb2 = rb0 + 8;
            int cnt_i = 0, mx_i = INT_MIN;
#pragma unroll 4
            for (int t = 0; t < 16; ++t) {
                const int o = 16 * t;
                i32x4 ah0 = RDH(rb0 + o), al0 = RDL(rb0 + o);
                i32x4 ah1 = RDH(rb1 + o), al1 = RDL(rb1 + o);
                i32x4 ah2 = RDH(rb2 + o), al2 = RDL(rb2 + o);
                i32x4 a0 = {0,0,0,0}, a1x = {0,0,0,0};
                i32x4 a1y = {0,0,0,0}, a2 = {0,0,0,0};
                mfma_step(ah0, al0, C0, D0, a0, a1x, a1y, a2);
                mfma_step(ah1, al1, C1, D1, a0, a1x, a1y, a2);
                mfma_step(ah2, al2, C2, D2, a0, a1x, a1y, a2);
                tile_stats(a0, a1x, a1y, a2, tj, cnt_i, mx_i);
            }
            flush(j, cnt_i, mx_i);
        }

        // ---- d=2: windowed via stride-8 alias (step2@t == step0@t+1) ----
        {
            const int j = 1;
            const i32x4 C0 = wcv[(3 + 0) * 64 + lane];
            const i32x4 C1 = wcv[(3 + 1) * 64 + lane];
            const i32x4 C2 = wcv[(3 + 2) * 64 + lane];
            const i32x4 D0 = wdv[(3 + 0) * 64 + lane];
            const i32x4 D1 = wdv[(3 + 1) * 64 + lane];
            const i32x4 D2 = wdv[(3 + 2) * 64 + lane];
            const int tj = (int)floorf(bias_tab[16 + row_l] * -33554432.0f);
            const int rb = HALO + wv * 256 + row_l + (q - 5) * 2;
            i32x4 s0h = RDH(rb), s0l = RDL(rb);
            int cnt_i = 0, mx_i = INT_MIN;
#pragma unroll
            for (int t = 0; t < 16; ++t) {
                i32x4 g1h = RDH(rb + 16 * t + 8);
                i32x4 g1l = RDL(rb + 16 * t + 8);
                i32x4 s2h = RDH(rb + 16 * t + 16);   // = step0 of tile t+1
                i32x4 s2l = RDL(rb + 16 * t + 16);
                i32x4 a0 = {0,0,0,0}, a1x = {0,0,0,0};
                i32x4 a1y = {0,0,0,0}, a2 = {0,0,0,0};
                mfma_step(s0h, s0l, C0, D0, a0, a1x, a1y, a2);
                mfma_step(g1h, g1l, C1, D1, a0, a1x, a1y, a2);
                mfma_step(s2h, s2l, C2, D2, a0, a1x, a1y, a2);
                tile_stats(a0, a1x, a1y, a2, tj, cnt_i, mx_i);
                s0h = s2h; s0l = s2l;
            }
            flush(j, cnt_i, mx_i);
        }

        // ---- d=4..32: windowed paths ----
        win3  (2, (q - 5) * 4);        // d=4,  taps q+4k,  stride 16
        win3x2(3, (q - 5) * 8);        // d=8,  taps q+4k,  stride 32
        win3  (4, (3 * q - 5) * 16);   // d=16, taps 3q+k,  stride 16
        win3x2(5, (3 * q - 5) * 32);   // d=32, taps 3q+k,  stride 32
    }

    __syncthreads();
    if (tid < 96) {
        const int jj = tid >> 4, s = tid & 15;
        if (s < 15) {
            const int c = scnt[jj * 16 + s];
            const int m = smx[jj * 16 + s];
            const float bj = bias_tab[jj * 16 + s];
            const int ks = s / 5, f = s % 5;
            const int gg = jj * 5 + f;
            const size_t base =
                ((((size_t)ks * N_SAMP + n) * NCHUNK + ch) * NFILT + gg) * 2;
            ws[base]     = (float)c;
            ws[base + 1] = bj + (float)m * 2.9802322387695312e-8f; // 2^-25
        }
    }
#undef RDH
#undef RDL
}

// ---------------------------------------------------------------------------
// Reduce chunks -> feature value, then per-feature batch norm.
// ---------------------------------------------------------------------------
__global__ __launch_bounds__(512)
void rocket_finish(const float* __restrict__ ws, float* __restrict__ out)
{
    const int i = blockIdx.x;
    const int t = threadIdx.x;

    const int ks = i / 60;
    const int r  = i % 60;
    const int g  = r >> 1;
    const int m  = r & 1;

    const size_t base =
        ((((size_t)ks * N_SAMP + t) * NCHUNK) * NFILT + g) * 2 + m;

    float v;
    if (m) {
        v = -INFINITY;
#pragma unroll
        for (int c = 0; c < NCHUNK; ++c)
            v = fmaxf(v, ws[base + (size_t)c * NFILT * 2]);
    } else {
        v = 0.0f;
#pragma unroll
        for (int c = 0; c < NCHUNK; ++c)
            v += ws[base + (size_t)c * NFILT * 2];
        v *= (1.0f / (float)L_IN);
    }

    float s  = v;
    float sq = v * v;
#pragma unroll
    for (int off = 32; off; off >>= 1) {
        s  += __shfl_xor(s, off);
        sq += __shfl_xor(sq, off);
    }

    __shared__ float ss[8], sqq[8];
    const int lane = t & 63;
    const int wv   = t >> 6;
    if (lane == 0) { ss[wv] = s; sqq[wv] = sq; }
    __syncthreads();
    if (t == 0) {
        float S = 0.0f, Q = 0.0f;
#pragma unroll
        for (int w = 0; w < 8; ++w) { S += ss[w]; Q += sqq[w]; }
        ss[0] = S; sqq[0] = Q;
    }
    __syncthreads();

    const float mean = ss[0] * (1.0f / (float)N_SAMP);
    const float var  = sqq[0] * (1.0f / (float)N_SAMP) - mean * mean;
    out[t * NFEAT + i] = (v - mean) / sqrtf(var + EPSV);
}

// ---------------------------------------------------------------------------
extern "C" void kernel_launch(void* const* d_in, const int* in_sizes, int n_in,
                              void* d_out, int out_size, void* d_ws, size_t ws_size,
                              hipStream_t stream)
{
    const float* x   = (const float*)d_in[0];
    const float* W7  = (const float*)d_in[1];
    const float* b7  = (const float*)d_in[2];
    const float* W9  = (const float*)d_in[3];
    const float* b9  = (const float*)d_in[4];
    const float* W11 = (const float*)d_in[5];
    const float* b11 = (const float*)d_in[6];
    float* out = (float*)d_out;
    float* ws  = (float*)d_ws;                 // 1.47 MB partials + tables
    signed char* wc = (signed char*)(ws + WF_OFF);
    signed char* wd = wc + WTAB_B;
    float* bias_tab = (float*)(wd + WTAB_B);

    build_wb<<<5, 256, 0, stream>>>(W7, W9, W11, b7, b9, b11, wc, wd, bias_tab);

    dim3 grid(NCHUNK, N_SAMP);
    rocket_conv_i8<<<grid, 256, 0, stream>>>(x, wc, wd, bias_tab, ws);

    rocket_finish<<<NFEAT, 512, 0, stream>>>(ws, out);
}